// Round 15
// baseline (200.418 us; speedup 1.0000x reference)
//
#include <hip/hip_runtime.h>

#define N_NODES 50000
#define N_EDGES 800000
#define K_BR    8
#define BCAP    131072           // per-bucket slot capacity (2^17); mean fill 100K
#define MLP_SLOTS (K_BR * BCAP)  // 1,048,576
#define SCAN_BLOCKS 196          // ceil(50000/256)

typedef _Float16 h2 __attribute__((ext_vector_type(2)));
typedef _Float16 half8 __attribute__((ext_vector_type(8)));
typedef float f32x4 __attribute__((ext_vector_type(4)));

#define MFMA(a, b, c) __builtin_amdgcn_mfma_f32_16x16x32_f16((a), (b), (c), 0, 0, 0)

#define VAL_MASK 0x3FFFFFFFu
#define FLG_A    0x40000000u
#define FLG_P    0x80000000u

// ---------------- workspace layout (bytes) ----------------
// fbuf      : 800,000 rows x 64 B f16    @ 0           (51,200,000)
// payload   : MLP_SLOTS x 16 B           @ 51,200,000  (16,777,216) [fill-guarded]
// cnt(deg)  : N ints                     @ 67,977,216  (200,000)   [memset 0]
// bucketCur : 8 ints (fill counts)       @ 68,177,216  (32)        [memset 0]
// ps        : 196 uints (lookback)       @ 68,177,248  (800)       [memset 0]
// nodeStart : N ints                     @ 68,178,048  (200,000)
// w1f4      : 2048 uint4 (B-frags L1)    @ 68,378,048  (32,768)
// w2f4      : 1024 uint4 (B-frags L2)    @ 68,410,816  (16,384)
// xh        : 50,000 x 32 f16            @ 68,427,200  (3,200,000)
// total: 71,627,200  (< proven ws floor 109,473,920)

__device__ __forceinline__ int branch_idx(float dx, float dy) {
    return (dx > 0.0f ? 1 : 0) + (dy > 0.0f ? 2 : 0) +
           ((fabsf(dx) - fabsf(dy)) > 0.0f ? 4 : 0);
}

__device__ __forceinline__ unsigned pk_f16pair(float a, float b) {
    h2 p; p.x = (_Float16)a; p.y = (_Float16)b;
    return __builtin_bit_cast(unsigned, p);
}

__device__ __forceinline__ unsigned short f16bits(float a) {
    _Float16 h = (_Float16)a;
    return __builtin_bit_cast(unsigned short, h);
}

// ONE pass over edges (absorbs prep). R15: ALL barriers before the 800K
// scattered cnt atomics are issued — CDNA s_barrier drains vmcnt(0), so an
// atomic issued before a barrier stalls the whole block on its return
// (R14: 53us, VALUBusy 1.4%). Post-barrier phase has no barriers: each
// wave's tail is only its own vmcnt, hidden across ~60% occupancy.
__global__ void pass1_kernel(const int* __restrict__ ei, const float* __restrict__ pos,
                             const float* __restrict__ ea, const float* __restrict__ ew,
                             const float* __restrict__ x,
                             const float* __restrict__ W1, const float* __restrict__ W2,
                             int* __restrict__ cnt, int* __restrict__ bucketCur,
                             uint4* __restrict__ payload, unsigned* __restrict__ xh,
                             uint4* __restrict__ w1f4, uint4* __restrict__ w2f4) {
    __shared__ int h[K_BR];
    __shared__ int base[K_BR];
    int t = threadIdx.x;
    int e = blockIdx.x * 256 + t;
    if (t < K_BR) h[t] = 0;
    __syncthreads();

    // phase 1: what the histogram needs, nothing else
    int s = ei[e], d = ei[N_EDGES + e];
    float2 ps = ((const float2*)pos)[s];
    float2 pd = ((const float2*)pos)[d];
    int k = branch_idx(ps.x - pd.x, ps.y - pd.y);
    int rank = atomicAdd(&h[k], 1);
    __syncthreads();
    if (t < K_BR) base[t] = (h[t] > 0) ? atomicAdd(&bucketCur[t], h[t]) : 0;
    __syncthreads();

    // phase 2: NO barriers from here on
    int slotLocal = atomicAdd(&cnt[d], 1);      // long-latency RMW, own-wave wait only
    float4 eav = ((const float4*)ea)[e];
    unsigned ewh = (unsigned)f16bits(ew[e]);

    // x mirror: one float2 per thread (f16 pair; 3125*256 = 800000 exact)
    float2 xv = ((const float2*)x)[e];
    xh[e] = pk_f16pair(xv.x, xv.y);

    // W fragments (first 12 blocks only): B[k=quad*8+j][n=lane&15] (m120)
    if (e < 2048) {                           // layer-1 B frags
        int L = e & 63, fl = e >> 6;
        int nt = fl & 1, kt = (fl >> 1) & 1, kk = fl >> 2;
        int quad = L >> 4, col = L & 15;
        unsigned dw[4];
#pragma unroll
        for (int i = 0; i < 4; ++i) {
            float v0 = 0.0f, v1 = 0.0f;
            int k0 = kt * 32 + quad * 8 + 2 * i;
            if (k0 < 36)     v0 = W1[kk * 1152 + k0 * 32 + nt * 16 + col];
            if (k0 + 1 < 36) v1 = W1[kk * 1152 + (k0 + 1) * 32 + nt * 16 + col];
            dw[i] = pk_f16pair(v0, v1);
        }
        w1f4[e] = make_uint4(dw[0], dw[1], dw[2], dw[3]);
    } else if (e < 3072) {                    // layer-2 B frags
        int u2 = e - 2048;
        int L = u2 & 63, fl = u2 >> 6;
        int nt = fl & 1, kk = fl >> 1;
        int quad = L >> 4, col = L & 15;
        unsigned dw[4];
#pragma unroll
        for (int i = 0; i < 4; ++i) {
            int k0 = quad * 8 + 2 * i;
            dw[i] = pk_f16pair(W2[kk * 1024 + k0 * 32 + nt * 16 + col],
                               W2[kk * 1024 + (k0 + 1) * 32 + nt * 16 + col]);
        }
        w2f4[u2] = make_uint4(dw[0], dw[1], dw[2], dw[3]);
    }

    int idx = (k << 17) + base[k] + rank;
    payload[idx] = make_uint4((unsigned)s | ((unsigned)d << 16),
                              (unsigned)slotLocal | (ewh << 16),
                              pk_f16pair(eav.x, eav.y),
                              pk_f16pair(eav.z, eav.w));
}

// single-dispatch decoupled-lookback exclusive scan (R11-proven).
__global__ void scan_kernel(const int* __restrict__ cnt, unsigned* __restrict__ ps,
                            int* __restrict__ nodeStart) {
    __shared__ int s[256];
    __shared__ int sh_off;
    int t = threadIdx.x, b = blockIdx.x;
    int i = b * 256 + t;
    int v = (i < N_NODES) ? cnt[i] : 0;
    s[t] = v;
    __syncthreads();
#pragma unroll
    for (int off = 1; off < 256; off <<= 1) {
        int tmp = (t >= off) ? s[t - off] : 0;
        __syncthreads();
        s[t] += tmp;
        __syncthreads();
    }
    int excl = s[t] - v;
    if (t == 255)
        atomicExch(&ps[b], (unsigned)s[255] | (b == 0 ? FLG_P : FLG_A));
    if (t == 0) sh_off = 0;
    if (t < 64 && b > 0) {   // wave-parallel lookback in wave 0
        int off = 0;
        int base = b - 1;
        for (;;) {
            int idx = base - t;
            unsigned w = 0;
            if (idx >= 0) {
                do { w = atomicOr(&ps[idx], 0u); } while (!(w & (FLG_A | FLG_P)));
            }
            bool isP = (w & FLG_P) != 0;
            unsigned long long pm = __ballot(isP);
            int firstP = pm ? (__ffsll((unsigned long long)pm) - 1) : 64;
            int contrib = (idx >= 0 && t <= firstP) ? (int)(w & VAL_MASK) : 0;
#pragma unroll
            for (int sh = 32; sh > 0; sh >>= 1) contrib += __shfl_down(contrib, sh, 64);
            contrib = __shfl(contrib, 0, 64);
            off += contrib;
            if (firstP < 64 || base - 64 < 0) break;
            base -= 64;
        }
        if (t == 0) sh_off = off;
    }
    __syncthreads();
    if (i < N_NODES) nodeStart[i] = excl + sh_off;
}

// MFMA MLP (R12-verified layouts; R14: 64-thread single-wave blocks,
// LDS 10,496 B -> 15 blocks/CU; f16 xh -> packed half8 m-staging).
__global__ void __launch_bounds__(64) mlp_kernel(
    const uint4* __restrict__ payload,
    const unsigned* __restrict__ xh,
    const uint4* __restrict__ w1f4, const float* __restrict__ b1,
    const uint4* __restrict__ w2f4, const float* __restrict__ b2,
    const int* __restrict__ nodeStart,
    const int* __restrict__ bucketFill,
    unsigned short* __restrict__ fbuf) {
    // m = 64 rows x 144B (9216) + h = 16 rows x 80B (1280) = 10,496 B
    __shared__ uint4 lds4[656];
    char* mreg = (char*)lds4;
    char* hreg = mreg + 9216;

    int t = blockIdx.x * 64 + threadIdx.x;
    int u = __builtin_amdgcn_readfirstlane(t);
    int k = u >> 17;
    int fill = bucketFill[k];
    if ((u & (BCAP - 1)) >= fill) return;   // whole wave past bucket fill
    int rel = t & (BCAP - 1);
    bool valid = rel < fill;
    int idx = (k << 17) + min(rel, fill - 1);  // clamp: pad slots are garbage

    int L = threadIdx.x;
    int quad = L >> 4, col = L & 15;

    uint4 pl = payload[idx];
    int s = (int)(pl.x & 0xFFFFu);
    int d = (int)(pl.x >> 16);
    _Float16 wh = __builtin_bit_cast(_Float16, (unsigned short)(pl.y >> 16));
    int slot = valid ? (nodeStart[d] + (int)(pl.y & 0xFFFFu)) : 0;

    // ---- stage m (f16, zero-padded k=36..63): packed half8 subtract ----
    const uint4* xj = ((const uint4*)xh) + 4 * (size_t)s;   // 64B f16 row
    const uint4* xi = ((const uint4*)xh) + 4 * (size_t)d;
    uint4* mrow = (uint4*)(mreg + L * 144);
#pragma unroll
    for (int q = 0; q < 4; ++q) {
        half8 a8 = __builtin_bit_cast(half8, xj[q]);
        half8 b8 = __builtin_bit_cast(half8, xi[q]);
        half8 d8 = a8 - b8;
        mrow[q] = __builtin_bit_cast(uint4, d8);
    }
    mrow[4] = make_uint4(pl.z, pl.w, 0u, 0u);
    mrow[5] = make_uint4(0u, 0u, 0u, 0u);
    mrow[6] = make_uint4(0u, 0u, 0u, 0u);
    mrow[7] = make_uint4(0u, 0u, 0u, 0u);

    // ---- B fragments (held in VGPRs; coalesced 16B/lane loads) ----
    half8 B1[2][2], B2[2];
#pragma unroll
    for (int kt = 0; kt < 2; ++kt)
#pragma unroll
        for (int nt = 0; nt < 2; ++nt)
            B1[kt][nt] = __builtin_bit_cast(half8, w1f4[((k * 2 + kt) * 2 + nt) * 64 + L]);
#pragma unroll
    for (int nt = 0; nt < 2; ++nt)
        B2[nt] = __builtin_bit_cast(half8, w2f4[(k * 2 + nt) * 64 + L]);
    float b1o0 = b1[k * 32 + col],      b1o1 = b1[k * 32 + 16 + col];
    float b2o0 = b2[k * 32 + col],      b2o1 = b2[k * 32 + 16 + col];

#pragma unroll
    for (int mt = 0; mt < 4; ++mt) {
        int arow = mt * 16 + col;
        half8 a0 = __builtin_bit_cast(half8, *(const uint4*)(mreg + arow * 144 + quad * 16));
        half8 a1 = __builtin_bit_cast(half8, *(const uint4*)(mreg + arow * 144 + 64 + quad * 16));
        f32x4 c0 = {b1o0, b1o0, b1o0, b1o0};
        f32x4 c1 = {b1o1, b1o1, b1o1, b1o1};
        c0 = MFMA(a0, B1[0][0], c0);
        c0 = MFMA(a1, B1[1][0], c0);
        c1 = MFMA(a0, B1[0][1], c1);
        c1 = MFMA(a1, B1[1][1], c1);
        // ReLU -> per-mt h buffer (16 edges x 32 ch, f16); wave-synchronous
#pragma unroll
        for (int r = 0; r < 4; ++r) {
            int er = quad * 4 + r;
            *(unsigned short*)(hreg + er * 80 + col * 2)        = f16bits(fmaxf(c0[r], 0.0f));
            *(unsigned short*)(hreg + er * 80 + (16 + col) * 2) = f16bits(fmaxf(c1[r], 0.0f));
        }
        // layer 2 for this mt
        half8 ah = __builtin_bit_cast(half8, *(const uint4*)(hreg + col * 80 + quad * 16));
        f32x4 d0 = {b2o0, b2o0, b2o0, b2o0};
        f32x4 d1 = {b2o1, b2o1, b2o1, b2o1};
        d0 = MFMA(ah, B2[0], d0);
        d1 = MFMA(ah, B2[1], d1);
#pragma unroll
        for (int r = 0; r < 4; ++r) {
            int edge = mt * 16 + quad * 4 + r;
            *(unsigned short*)(mreg + edge * 144 + col * 2)        = f16bits(fmaxf(d0[r], 0.0f));
            *(unsigned short*)(mreg + edge * 144 + (16 + col) * 2) = f16bits(fmaxf(d1[r], 0.0f));
        }
    }

    // ---- read back own edge's out row, *w (packed f16), store 64B ----
    half8 w8 = {wh, wh, wh, wh, wh, wh, wh, wh};
    uint4* orow = (uint4*)(mreg + L * 144);
    uint4* frow = (uint4*)(fbuf + 32 * (size_t)slot);
#pragma unroll
    for (int q = 0; q < 4; ++q) {
        half8 v8 = __builtin_bit_cast(half8, orow[q]);
        v8 = v8 * w8;
        if (valid) frow[q] = __builtin_bit_cast(uint4, v8);
    }
}

// 4 channels per thread: uint2 read = 4 f16; 8 threads/node cover a 64B row.
__global__ void agg_kernel(const unsigned short* __restrict__ fbuf,
                           const int* __restrict__ nodeStart, const int* __restrict__ deg,
                           const float* __restrict__ x, const float* __restrict__ Wr,
                           const float* __restrict__ br, float* __restrict__ out) {
    int t = blockIdx.x * blockDim.x + threadIdx.x;
    if (t >= N_NODES * 8) return;
    int n = t >> 3, g8 = t & 7;          // channels 4*g8 .. 4*g8+3
    int st = nodeStart[n], dg = deg[n];
    const uint2* fb = (const uint2*)fbuf;
    float a0 = 0.0f, a1 = 0.0f, a2 = 0.0f, a3 = 0.0f;
    for (int j = 0; j < dg; ++j) {
        uint2 uu = fb[(size_t)(st + j) * 8 + g8];   // CSR-contiguous stream
        h2 p01 = __builtin_bit_cast(h2, uu.x);
        h2 p23 = __builtin_bit_cast(h2, uu.y);
        a0 += (float)p01.x;
        a1 += (float)p01.y;
        a2 += (float)p23.x;
        a3 += (float)p23.y;
    }
    float inv = 1.0f / (float)max(dg, 1);
    int o = g8 * 4;
    a0 = a0 * inv + br[o];
    a1 = a1 * inv + br[o + 1];
    a2 = a2 * inv + br[o + 2];
    a3 = a3 * inv + br[o + 3];
    const float* xr = x + 32 * (size_t)n;
#pragma unroll
    for (int c = 0; c < 32; ++c) {
        float xv = xr[c];
        a0 = fmaf(xv, Wr[c * 32 + o], a0);
        a1 = fmaf(xv, Wr[c * 32 + o + 1], a1);
        a2 = fmaf(xv, Wr[c * 32 + o + 2], a2);
        a3 = fmaf(xv, Wr[c * 32 + o + 3], a3);
    }
    float4* o4 = (float4*)(out + 32 * (size_t)n + o);
    *o4 = make_float4(a0, a1, a2, a3);
}

extern "C" void kernel_launch(void* const* d_in, const int* in_sizes, int n_in,
                              void* d_out, int out_size, void* d_ws, size_t ws_size,
                              hipStream_t stream) {
    const float* x   = (const float*)d_in[0];
    const float* pos = (const float*)d_in[1];
    const int*   ei  = (const int*)d_in[2];
    const float* ea  = (const float*)d_in[3];
    const float* ew  = (const float*)d_in[4];
    const float* W1  = (const float*)d_in[5];
    const float* b1  = (const float*)d_in[6];
    const float* W2  = (const float*)d_in[7];
    const float* b2  = (const float*)d_in[8];
    const float* Wr  = (const float*)d_in[9];
    const float* br  = (const float*)d_in[10];
    float* out = (float*)d_out;

    char* ws = (char*)d_ws;
    unsigned short* fbuf = (unsigned short*)(ws + 0);
    uint4* payload  = (uint4*)(ws + 51200000);
    int* cnt        = (int*)(ws + 67977216);
    int* bucketCur  = (int*)(ws + 68177216);
    unsigned* psLb  = (unsigned*)(ws + 68177248);
    int* nodeStart  = (int*)(ws + 68178048);
    uint4* w1f4     = (uint4*)(ws + 68378048);
    uint4* w2f4     = (uint4*)(ws + 68410816);
    unsigned* xh    = (unsigned*)(ws + 68427200);

    hipMemsetAsync(cnt, 0, 200832, stream);  // cnt + bucketCur + ps (contiguous)

    pass1_kernel<<<N_EDGES / 256, 256, 0, stream>>>(ei, pos, ea, ew, x, W1, W2,
                                                    cnt, bucketCur, payload, xh,
                                                    w1f4, w2f4);
    scan_kernel<<<SCAN_BLOCKS, 256, 0, stream>>>(cnt, psLb, nodeStart);
    mlp_kernel<<<MLP_SLOTS / 64, 64, 0, stream>>>(payload, xh, w1f4, b1, w2f4, b2,
                                                  nodeStart, bucketCur, fbuf);
    agg_kernel<<<(N_NODES * 8 + 255) / 256, 256, 0, stream>>>(fbuf, nodeStart, cnt,
                                                              x, Wr, br, out);
}